// Round 11
// baseline (60.289 us; speedup 1.0000x reference)
//
#include <hip/hip_runtime.h>
#include <hip/hip_bf16.h>

// ws layout (requires ws_size >= 17039360 B):
//   [0, 221184)        : weights as bf16 in 32x32x16 MFMA B-fragment order
//   [221184, 221440)   : 256 B of zeros (OOB halo source)
//   [262144, 17039360) : x_t = x transposed to [b][s][c] bf16 (16 MiB)
#define WS_W_OFF    0
#define WS_ZERO_OFF 221184
#define WS_XT_OFF   262144

typedef __attribute__((ext_vector_type(8)))  short s16x8;
typedef __attribute__((ext_vector_type(4)))  float f32x4;
typedef __attribute__((ext_vector_type(16))) float f32x16;

#define GLOBAL_AS __attribute__((address_space(1)))
#define LDS_AS    __attribute__((address_space(3)))

__device__ __forceinline__ unsigned short f2bf(float f) {
  unsigned u = __builtin_bit_cast(unsigned, f);
  u = u + 0x7fffu + ((u >> 16) & 1u);
  return (unsigned short)(u >> 16);
}

// ---------------------------------------------------------------------------
// Fused prep (VERIFIED in round 7, byte-identical): blocks [0,432) repack
// weights into 32x32x16 B-fragments; blocks [432,4528) transpose x.
// Fragment f = nt*2+ks of (tap,h) holds B[n][k]: n = cout = nt*32 + (l&31),
// k(cin) = h*32 + ks*16 + (l>>5)*8 + j. bf16 index = (((tap*2+h)*4+f)*64+l)*8+j.
__global__ void prep_kernel(const float* __restrict__ x,
                            const float* __restrict__ w,
                            unsigned short* __restrict__ wsw,
                            float* __restrict__ zeros,
                            unsigned short* __restrict__ xt) {
  int blk = blockIdx.x;
  if (blk < 432) {
    int t = blk * 256 + threadIdx.x;             // 110592 threads exactly
    int tap  = t % 27;
    int cin  = (t / 27) & 63;
    int cout = t / (27 * 64);
    int h  = cin >> 5;
    int c5 = cin & 31;
    int ks = c5 >> 4;
    int hi = (c5 >> 3) & 1;
    int j  = c5 & 7;
    int nt = cout >> 5;
    int l  = hi * 32 + (cout & 31);
    int f  = nt * 2 + ks;
    int dst = (((tap * 2 + h) * 4 + f) * 64 + l) * 8 + j;
    wsw[dst] = f2bf(w[t]);
    if (t < 64) zeros[t] = 0.0f;
  } else {
    int t  = (blk - 432) * 256 + threadIdx.x;    // 1048576 threads
    int s  = t & 32767;
    int c8 = (t >> 15) & 7;
    int b  = t >> 18;
    const float* src = x + (size_t)(b * 64 + c8 * 8) * 32768 + s;
    s16x8 v;
    #pragma unroll
    for (int k = 0; k < 8; ++k) v[k] = (short)f2bf(src[(size_t)k * 32768]);
    *(s16x8*)(xt + (size_t)(b * 32768 + s) * 64 + c8 * 8) = v;
  }
}

// ---------------------------------------------------------------------------
// Implicit-GEMM conv, 32x32x16 MFMA, M_w = 128 / N_w = 32 (halved B-traffic
// per wave, 17% lower MFMA wall than 16x16x32).
// Block = (b, z-quad, y-quad): 4z x 4y x 32x = 512 outputs x 64 couts,
// 512 threads = 8 waves, grid 256 = 1 block/CU. Wave w: z-row zo = w>>1,
// cout-half nh = w&1; per wave 4 m-frags (y-rows, each 32x wide) x 1 n-frag
// (32 couts): acc[4] f32x16 = 64 VGPR. K = 64 as two cin-halves of 32
// (2 k-steps each); same acc accumulates across halves -> no reduction.
// Tap loop: fully unrolled, ZERO barriers (3 barriers total in the kernel).
//
// Halo: pos p (1224 = 6z*6y*34x) at halo[p*64]; 16B chunk c stored at slot
// c ^ ((p>>1)&3)  (the R7-VERIFIED swizzle family). A-read (lane l: p =
// p0 + (l&31), c = ks*2 + (l>>5)): groups (l&1, l>>5) x slot-spread give
// exactly 8 of the wave's 256 dwords per bank -> ds_read_b128 floor.
// Staging dest LINEAR (halo + r*8192 + tid*16); swizzle on SOURCE chunk
// csrc = (tid&3) ^ ((tid>>3)&3)  (valid: pos base r*128 == 0 mod 8).
__global__ __launch_bounds__(512, 2) void conv_kernel(const float* __restrict__ bias,
                                                      float* __restrict__ out,
                                                      const char* __restrict__ ws) {
  __shared__ __align__(16) unsigned char halo[1224 * 64];   // 78336 B

  const int tid  = threadIdx.x;
  const int lane = tid & 63;
  const int w    = tid >> 6;                     // wave 0..7
  const int zo   = w >> 1;                       // z-row within quad
  const int nh   = w & 1;                        // cout half
  // XCD swizzle (256 % 8 == 0 -> bijective): 32 contiguous logical blocks per
  // XCD (fixed b, 4 consecutive z-quads) -> x_t slab mostly L2-resident.
  const int logical = (blockIdx.x & 7) * 32 + (blockIdx.x >> 3);
  const int yq = logical & 7, zq = (logical >> 3) & 7, b = logical >> 6;
  const int z0 = zq * 4, y0 = yq * 4;

  const int q31 = lane & 31;
  const int hi  = lane >> 5;

  // ---- halo staging: 1224 pos x 64 B per half; 10 rounds x 128 pos ----
  const int csrc = ((tid & 3) ^ ((tid >> 3) & 3)) * 16;

  auto stage = [&](int h) {
    #pragma unroll 1
    for (int r = 0; r < 10; ++r) {
      int pos = r * 128 + (tid >> 2);
      if (pos < 1224) {
        int hz = pos / 204; int rem = pos - hz * 204;      // 204 = 6*34
        int hy = rem / 34;  int hx = rem - hy * 34;
        int gz = z0 + hz - 1, gy = y0 + hy - 1, gx = hx - 1;
        bool inb = ((unsigned)gz < 32u) & ((unsigned)gy < 32u) &
                   ((unsigned)gx < 32u);
        int s = (gz * 32 + gy) * 32 + gx;
        int src = inb ? (WS_XT_OFF + (b * 32768 + s) * 128 + h * 64 + csrc)
                      : WS_ZERO_OFF;
        __builtin_amdgcn_global_load_lds(
            (const GLOBAL_AS void*)(ws + src),
            (LDS_AS void*)(&halo[r * 8192 + tid * 16]),
            16, 0, 0);
      }
    }
  };

  const s16x8* __restrict__ wfr = (const s16x8*)(ws + WS_W_OFF);

  f32x16 acc[4];
  #pragma unroll
  for (int mt = 0; mt < 4; ++mt)
    #pragma unroll
    for (int r = 0; r < 16; ++r) acc[mt][r] = 0.0f;

  // 27 taps per half, fully unrolled, zero barriers.
  auto run27 = [&](int h) {
    #pragma unroll
    for (int tap = 0; tap < 27; ++tap) {
      const int kd = tap / 9, r9 = tap % 9;
      const int kh = r9 / 3, kw = r9 % 3;        // compile-time constants
      s16x8 Bf[2], Af[4][2];
      #pragma unroll
      for (int ks = 0; ks < 2; ++ks)
        Bf[ks] = wfr[((tap * 2 + h) * 4 + nh * 2 + ks) * 64 + lane];
      #pragma unroll
      for (int mt = 0; mt < 4; ++mt) {
        int p = ((zo + kd) * 6 + mt + kh) * 34 + kw + q31;
        #pragma unroll
        for (int ks = 0; ks < 2; ++ks) {
          int slot = ((ks << 1) | hi) ^ ((p >> 1) & 3);
          Af[mt][ks] = *(const s16x8*)&halo[(p << 6) + (slot << 4)];
        }
      }
      __builtin_amdgcn_s_setprio(1);
      #pragma unroll
      for (int mt = 0; mt < 4; ++mt)
        #pragma unroll
        for (int ks = 0; ks < 2; ++ks)
          acc[mt] = __builtin_amdgcn_mfma_f32_32x32x16_bf16(
              Af[mt][ks], Bf[ks], acc[mt], 0, 0, 0);
      __builtin_amdgcn_s_setprio(0);
    }
  };

  stage(0);
  __syncthreads();                   // drains gload_lds; halo 0 ready
  run27(0);
  __syncthreads();                   // all waves done reading halo 0
  stage(1);
  __syncthreads();                   // halo 1 ready
  run27(1);

  // ---- epilogue: 32x32 C/D layout (m74/m101, R7-verified):
  // col(cout) = nh*32 + (lane&31), row(x) = (reg&3) + 8*(reg>>2) + 4*(lane>>5)
  const int z = z0 + zo;
  const int cout = nh * 32 + q31;
  const float bv = bias[cout];
  #pragma unroll
  for (int mt = 0; mt < 4; ++mt) {
    int y = y0 + mt;
    float* orow = out + ((size_t)((b * 64 + cout) * 32 + z) * 32 + y) * 32;
    #pragma unroll
    for (int q = 0; q < 4; ++q) {
      int x0 = q * 8 + hi * 4;
      f32x4 v;
      #pragma unroll
      for (int r = 0; r < 4; ++r) v[r] = acc[mt][q * 4 + r] + bv;
      *(f32x4*)&orow[x0] = v;
    }
  }
}

extern "C" void kernel_launch(void* const* d_in, const int* in_sizes, int n_in,
                              void* d_out, int out_size, void* d_ws, size_t ws_size,
                              hipStream_t stream) {
  const float* x    = (const float*)d_in[0];
  const float* wgt  = (const float*)d_in[1];
  const float* bias = (const float*)d_in[2];
  float* out = (float*)d_out;
  char* ws = (char*)d_ws;

  prep_kernel<<<4528, 256, 0, stream>>>(x, wgt,
                                        (unsigned short*)(ws + WS_W_OFF),
                                        (float*)(ws + WS_ZERO_OFF),
                                        (unsigned short*)(ws + WS_XT_OFF));
  conv_kernel<<<256, 512, 0, stream>>>(bias, out, ws);
}

// Round 12
// 46.251 us; speedup vs baseline: 1.3035x; 1.3035x over previous
//
#include <hip/hip_runtime.h>
#include <hip/hip_bf16.h>

// ws layout (requires ws_size >= 17039360 B):
//   [0, 221184)        : weights as bf16 in 16x16x32 MFMA B-fragment order
//   [221184, 221440)   : 256 B of zeros (OOB halo source)
//   [262144, 17039360) : x_t = x transposed to [b][s][c] bf16 (16 MiB)
#define WS_W_OFF    0
#define WS_ZERO_OFF 221184
#define WS_XT_OFF   262144

typedef __attribute__((ext_vector_type(8))) short s16x8;
typedef __attribute__((ext_vector_type(4))) float f32x4;

#define GLOBAL_AS __attribute__((address_space(1)))
#define LDS_AS    __attribute__((address_space(3)))

__device__ __forceinline__ unsigned short f2bf(float f) {
  unsigned u = __builtin_bit_cast(unsigned, f);
  u = u + 0x7fffu + ((u >> 16) & 1u);
  return (unsigned short)(u >> 16);
}

// ---------------------------------------------------------------------------
// Fused prep (VERIFIED rounds 5/9/10, byte-identical): blocks [0,432) repack
// weights into 16x16x32 B-fragments; blocks [432,4528) transpose x.
// Fragment f = (tap*2+h)*4+nf holds B[n][k] for n = nf*16 + (lane&15),
// cin = h*32 + (lane>>4)*8 + j. bf16 index = (f*64 + lane)*8 + j.
// The 4 KB tile for (tap,h) is contiguous at byte offset (tap*2+h)*4096.
__global__ void prep_kernel(const float* __restrict__ x,
                            const float* __restrict__ w,
                            unsigned short* __restrict__ wsw,
                            float* __restrict__ zeros,
                            unsigned short* __restrict__ xt) {
  int blk = blockIdx.x;
  if (blk < 432) {
    int t = blk * 256 + threadIdx.x;             // 110592 threads exactly
    int tap  = t % 27;
    int cin  = (t / 27) & 63;
    int cout = t / (27 * 64);
    int h   = cin >> 5;
    int q   = (cin >> 3) & 3;
    int j   = cin & 7;
    int nf  = cout >> 4;
    int lane = q * 16 + (cout & 15);
    int dst = (((tap * 2 + h) * 4 + nf) * 64 + lane) * 8 + j;
    wsw[dst] = f2bf(w[t]);
    if (t < 64) zeros[t] = 0.0f;
  } else {
    int t  = (blk - 432) * 256 + threadIdx.x;    // 1048576 threads
    int s  = t & 32767;
    int c8 = (t >> 15) & 7;
    int b  = t >> 18;
    const float* src = x + (size_t)(b * 64 + c8 * 8) * 32768 + s;
    s16x8 v;
    #pragma unroll
    for (int k = 0; k < 8; ++k) v[k] = (short)f2bf(src[(size_t)k * 32768]);
    *(s16x8*)(xt + (size_t)(b * 32768 + s) * 64 + c8 * 8) = v;
  }
}

// ---------------------------------------------------------------------------
// Implicit-GEMM conv: ALL-LDS operand feed (zero global traffic in tap loop).
// Block = (b, z-quad, y-quad): 4z x 4y x 32x = 512 outputs x 64 couts,
// 512 threads = 8 waves, grid 256 = exactly 1 block/CU, ONE generation.
// Wave w: zo = w>>1 (z-row), yo2 = (w&1)*2 (y-pair): M_w = 64, N_w = 64.
//
// LDS (152064 B, 1 block/CU):
//   halo  : cin-half A tile, 1224 pos (6z*6y*34x) x 64 B = 78336 B, LINEAR
//           (pos p at halo[p*64], 16B cin-chunk c at +c*16; A-read puts
//           exactly 8 of the wave's 256 dwords on each bank = b128 floor).
//   blds  : 2 x 36864 B = double-buffered 9-tap B group (kd-slice).
//           B-read (f*64+lane)*16 -> 8 dwords/bank = floor.
// Schedule per cin-half h: stage_halo(h) + stage_B(kd=0); barrier;
//   {stage_B(kd+1) issue -> 9-tap all-LDS compute -> barrier} x3.
// Every stage has a full ~5.6K-cy compute window before its consuming
// barrier, so the barrier's vmcnt drain is free (no mid-loop global waits).
__global__ __launch_bounds__(512, 1) void conv_kernel(const float* __restrict__ bias,
                                                      float* __restrict__ out,
                                                      const char* __restrict__ ws) {
  __shared__ __align__(16) unsigned char halo[1224 * 64];   // 78336 B
  __shared__ __align__(16) unsigned char blds[2][36864];    // 73728 B

  const int tid  = threadIdx.x;
  const int lane = tid & 63;
  const int w    = tid >> 6;                     // wave 0..7
  const int zo   = w >> 1;                       // z-row in quad
  const int yo2  = (w & 1) * 2;                  // y-pair base
  // XCD swizzle (256 % 8 == 0 -> bijective): 32 contiguous logical blocks
  // per XCD (fixed b, 4 consecutive z-quads) -> x_t slab L2-resident.
  const int logical = (blockIdx.x & 7) * 32 + (blockIdx.x >> 3);
  const int yq = logical & 7, zq = (logical >> 3) & 7, b = logical >> 6;
  const int z0 = zq * 4, y0 = yq * 4;

  const int r15 = lane & 15;
  const int hi4 = lane >> 4;

  // ---- halo staging: 4896 16B chunks, 10 rounds, all-linear dest ----
  auto stage_halo = [&](int h) {
    #pragma unroll 1
    for (int r = 0; r < 10; ++r) {
      int ci = r * 512 + tid;
      if (ci < 4896) {
        int pos = ci >> 2, ch = ci & 3;
        int hz = pos / 204; int rem = pos - hz * 204;      // 204 = 6*34
        int hy = rem / 34;  int hx = rem - hy * 34;
        int gz = z0 + hz - 1, gy = y0 + hy - 1, gx = hx - 1;
        bool inb = ((unsigned)gz < 32u) & ((unsigned)gy < 32u) &
                   ((unsigned)gx < 32u);
        int s = (gz * 32 + gy) * 32 + gx;
        int src = inb ? (WS_XT_OFF + (b * 32768 + s) * 128 + h * 64 + ch * 16)
                      : WS_ZERO_OFF;
        __builtin_amdgcn_global_load_lds(
            (const GLOBAL_AS void*)(ws + src),
            (LDS_AS void*)(&halo[ci * 16]),
            16, 0, 0);
      }
    }
  };

  // ---- B staging: one kd-group = 9 taps x 4 KB = 2304 chunks, 5 rounds ----
  auto stage_B = [&](int h, int kd, int buf) {
    #pragma unroll 1
    for (int r = 0; r < 5; ++r) {
      int ci = r * 512 + tid;
      if (ci < 2304) {
        int tl = ci >> 8, off = ci & 255;
        int src = WS_W_OFF + ((kd * 9 + tl) * 2 + h) * 4096 + off * 16;
        __builtin_amdgcn_global_load_lds(
            (const GLOBAL_AS void*)(ws + src),
            (LDS_AS void*)(&blds[buf][ci * 16]),
            16, 0, 0);
      }
    }
  };

  f32x4 zero4 = {0.f, 0.f, 0.f, 0.f};
  f32x4 acc[4][4];
  #pragma unroll
  for (int mf = 0; mf < 4; ++mf)
    #pragma unroll
    for (int nf = 0; nf < 4; ++nf) acc[mf][nf] = zero4;

  // ---- 9 taps of one kd-slice, all operands from LDS, zero barriers ----
  auto run9 = [&](int kd, int buf) {
    #pragma unroll
    for (int tl = 0; tl < 9; ++tl) {
      const int kh = tl / 3, kw = tl % 3;        // compile-time
      s16x8 Bf[4], Af[4];
      #pragma unroll
      for (int nf = 0; nf < 4; ++nf)
        Bf[nf] = *(const s16x8*)&blds[buf][(tl * 256 + nf * 64 + lane) * 16];
      #pragma unroll
      for (int mf = 0; mf < 4; ++mf) {
        int p = ((zo + kd) * 6 + yo2 + (mf >> 1) + kh) * 34
              + kw + (mf & 1) * 16 + r15;
        Af[mf] = *(const s16x8*)&halo[p * 64 + hi4 * 16];
      }
      __builtin_amdgcn_s_setprio(1);
      #pragma unroll
      for (int mf = 0; mf < 4; ++mf)
        #pragma unroll
        for (int nf = 0; nf < 4; ++nf)
          acc[mf][nf] = __builtin_amdgcn_mfma_f32_16x16x32_bf16(
              Af[mf], Bf[nf], acc[mf][nf], 0, 0, 0);
      __builtin_amdgcn_s_setprio(0);
    }
  };

  // ---- half 0 ----
  stage_halo(0); stage_B(0, 0, 0);
  __syncthreads();                   // halo0 + B(kd0) ready
  stage_B(0, 1, 1);
  run9(0, 0);
  __syncthreads();                   // B(kd1) landed (free drain)
  stage_B(0, 2, 0);                  // buf0 free: kd0 reads done pre-barrier
  run9(1, 1);
  __syncthreads();                   // B(kd2) landed
  run9(2, 0);
  __syncthreads();                   // all halo0/blds reads done

  // ---- half 1 ----
  stage_halo(1); stage_B(1, 0, 1);
  __syncthreads();
  stage_B(1, 1, 0);
  run9(0, 1);
  __syncthreads();
  stage_B(1, 2, 1);
  run9(1, 0);
  __syncthreads();
  run9(2, 1);

  // ---- epilogue (R5-verified 16x16 C/D): full 64B-line coalesced stores ----
  const int z = z0 + zo;
  #pragma unroll
  for (int nf = 0; nf < 4; ++nf) {
    int cout = nf * 16 + r15;
    float bv = bias[cout];
    #pragma unroll
    for (int mf = 0; mf < 4; ++mf) {
      int y  = y0 + yo2 + (mf >> 1);
      int x0 = (mf & 1) * 16 + 4 * hi4;
      float* orow = out + ((size_t)((b * 64 + cout) * 32 + z) * 32 + y) * 32;
      f32x4 v;
      #pragma unroll
      for (int r = 0; r < 4; ++r) v[r] = acc[mf][nf][r] + bv;
      *(f32x4*)&orow[x0] = v;
    }
  }
}

extern "C" void kernel_launch(void* const* d_in, const int* in_sizes, int n_in,
                              void* d_out, int out_size, void* d_ws, size_t ws_size,
                              hipStream_t stream) {
  const float* x    = (const float*)d_in[0];
  const float* wgt  = (const float*)d_in[1];
  const float* bias = (const float*)d_in[2];
  float* out = (float*)d_out;
  char* ws = (char*)d_ws;

  prep_kernel<<<4528, 256, 0, stream>>>(x, wgt,
                                        (unsigned short*)(ws + WS_W_OFF),
                                        (float*)(ws + WS_ZERO_OFF),
                                        (unsigned short*)(ws + WS_XT_OFF));
  conv_kernel<<<256, 512, 0, stream>>>(bias, out, ws);
}

// Round 13
// 46.095 us; speedup vs baseline: 1.3079x; 1.0034x over previous
//
#include <hip/hip_runtime.h>
#include <hip/hip_bf16.h>

// ws layout (requires ws_size >= 17039360 B):
//   [0, 221184)        : weights as bf16 in 16x16x32 MFMA B-fragment order
//   [221184, 221440)   : 256 B of zeros (OOB halo source)
//   [262144, 17039360) : x_t = x transposed to [b][s][c] bf16 (16 MiB)
#define WS_W_OFF    0
#define WS_ZERO_OFF 221184
#define WS_XT_OFF   262144

typedef __attribute__((ext_vector_type(8))) short s16x8;
typedef __attribute__((ext_vector_type(4))) float f32x4;

#define GLOBAL_AS __attribute__((address_space(1)))
#define LDS_AS    __attribute__((address_space(3)))

__device__ __forceinline__ unsigned short f2bf(float f) {
  unsigned u = __builtin_bit_cast(unsigned, f);
  u = u + 0x7fffu + ((u >> 16) & 1u);
  return (unsigned short)(u >> 16);
}

// ---------------------------------------------------------------------------
// Fused prep (VERIFIED rounds 5/9/10/12, byte-identical): blocks [0,432)
// repack weights into 16x16x32 B-fragments; blocks [432,4528) transpose x.
// Fragment f = (tap*2+h)*4+nf holds B[n][k] for n = nf*16 + (lane&15),
// cin = h*32 + (lane>>4)*8 + j. bf16 index = (f*64 + lane)*8 + j.
// The 4 KB tile for (tap,h) is contiguous at byte offset (tap*2+h)*4096.
__global__ void prep_kernel(const float* __restrict__ x,
                            const float* __restrict__ w,
                            unsigned short* __restrict__ wsw,
                            float* __restrict__ zeros,
                            unsigned short* __restrict__ xt) {
  int blk = blockIdx.x;
  if (blk < 432) {
    int t = blk * 256 + threadIdx.x;             // 110592 threads exactly
    int tap  = t % 27;
    int cin  = (t / 27) & 63;
    int cout = t / (27 * 64);
    int h   = cin >> 5;
    int q   = (cin >> 3) & 3;
    int j   = cin & 7;
    int nf  = cout >> 4;
    int lane = q * 16 + (cout & 15);
    int dst = (((tap * 2 + h) * 4 + nf) * 64 + lane) * 8 + j;
    wsw[dst] = f2bf(w[t]);
    if (t < 64) zeros[t] = 0.0f;
  } else {
    int t  = (blk - 432) * 256 + threadIdx.x;    // 1048576 threads
    int s  = t & 32767;
    int c8 = (t >> 15) & 7;
    int b  = t >> 18;
    const float* src = x + (size_t)(b * 64 + c8 * 8) * 32768 + s;
    s16x8 v;
    #pragma unroll
    for (int k = 0; k < 8; ++k) v[k] = (short)f2bf(src[(size_t)k * 32768]);
    *(s16x8*)(xt + (size_t)(b * 32768 + s) * 64 + c8 * 8) = v;
  }
}

// ---------------------------------------------------------------------------
// Implicit-GEMM conv: ALL-LDS operand feed + WAVE-STAGGERED tap order.
// Identical to round 12 except run9: wave w processes the 9 (kh,kw) taps of
// each kd-group in kh-rotated order (rot = w % 3). The tap sum is
// order-invariant and all operands are LDS-resident at group start, so this
// is a pure reorder -- it desynchronizes the waves' read/MFMA phases so the
// LDS pipe and matrix pipe run CONCURRENTLY instead of back-to-back
// (the 36-us plateau across rounds 5-12 matches sum-of-pipes exactly).
//
// Block = (b, z-quad, y-quad): 4z x 4y x 32x = 512 outputs x 64 couts,
// 512 threads = 8 waves, grid 256 = exactly 1 block/CU, ONE generation.
// Wave w: zo = w>>1 (z-row), yo2 = (w&1)*2 (y-pair): M_w = 64, N_w = 64.
//
// LDS (152064 B): halo 1224 pos x 64 B (LINEAR: pos p at halo[p*64], chunk c
// at +c*16; A-read = 8 dwords/bank = b128 floor) + blds 2 x 36864 B
// (double-buffered 9-tap B group; B-read = 8 dwords/bank = floor).
__global__ __launch_bounds__(512, 1) void conv_kernel(const float* __restrict__ bias,
                                                      float* __restrict__ out,
                                                      const char* __restrict__ ws) {
  __shared__ __align__(16) unsigned char halo[1224 * 64];   // 78336 B
  __shared__ __align__(16) unsigned char blds[2][36864];    // 73728 B

  const int tid  = threadIdx.x;
  const int lane = tid & 63;
  const int w    = tid >> 6;                     // wave 0..7
  const int zo   = w >> 1;                       // z-row in quad
  const int yo2  = (w & 1) * 2;                  // y-pair base
  const int rot  = w - (w >= 3 ? 3 : 0) - (w >= 6 ? 3 : 0);   // w % 3
  // XCD swizzle (256 % 8 == 0 -> bijective): 32 contiguous logical blocks
  // per XCD (fixed b, 4 consecutive z-quads) -> x_t slab L2-resident.
  const int logical = (blockIdx.x & 7) * 32 + (blockIdx.x >> 3);
  const int yq = logical & 7, zq = (logical >> 3) & 7, b = logical >> 6;
  const int z0 = zq * 4, y0 = yq * 4;

  const int r15 = lane & 15;
  const int hi4 = lane >> 4;

  // ---- halo staging: 4896 16B chunks, 10 rounds, all-linear dest ----
  auto stage_halo = [&](int h) {
    #pragma unroll 1
    for (int r = 0; r < 10; ++r) {
      int ci = r * 512 + tid;
      if (ci < 4896) {
        int pos = ci >> 2, ch = ci & 3;
        int hz = pos / 204; int rem = pos - hz * 204;      // 204 = 6*34
        int hy = rem / 34;  int hx = rem - hy * 34;
        int gz = z0 + hz - 1, gy = y0 + hy - 1, gx = hx - 1;
        bool inb = ((unsigned)gz < 32u) & ((unsigned)gy < 32u) &
                   ((unsigned)gx < 32u);
        int s = (gz * 32 + gy) * 32 + gx;
        int src = inb ? (WS_XT_OFF + (b * 32768 + s) * 128 + h * 64 + ch * 16)
                      : WS_ZERO_OFF;
        __builtin_amdgcn_global_load_lds(
            (const GLOBAL_AS void*)(ws + src),
            (LDS_AS void*)(&halo[ci * 16]),
            16, 0, 0);
      }
    }
  };

  // ---- B staging: one kd-group = 9 taps x 4 KB = 2304 chunks, 5 rounds ----
  auto stage_B = [&](int h, int kd, int buf) {
    #pragma unroll 1
    for (int r = 0; r < 5; ++r) {
      int ci = r * 512 + tid;
      if (ci < 2304) {
        int tl = ci >> 8, off = ci & 255;
        int src = WS_W_OFF + ((kd * 9 + tl) * 2 + h) * 4096 + off * 16;
        __builtin_amdgcn_global_load_lds(
            (const GLOBAL_AS void*)(ws + src),
            (LDS_AS void*)(&blds[buf][ci * 16]),
            16, 0, 0);
      }
    }
  };

  f32x4 zero4 = {0.f, 0.f, 0.f, 0.f};
  f32x4 acc[4][4];
  #pragma unroll
  for (int mf = 0; mf < 4; ++mf)
    #pragma unroll
    for (int nf = 0; nf < 4; ++nf) acc[mf][nf] = zero4;

  // ---- 9 taps of one kd-slice, all-LDS, kh rotated by wave (stagger) ----
  auto run9 = [&](int kd, int buf) {
    #pragma unroll
    for (int tl = 0; tl < 9; ++tl) {
      const int kh0 = tl / 3, kw = tl % 3;       // compile-time
      int kh = kh0 + rot; if (kh >= 3) kh -= 3;  // wave-uniform runtime rotate
      int tle = kh * 3 + kw;                     // B tap index (LDS addr only)
      s16x8 Bf[4], Af[4];
      #pragma unroll
      for (int nf = 0; nf < 4; ++nf)
        Bf[nf] = *(const s16x8*)&blds[buf][(tle * 256 + nf * 64 + lane) * 16];
      #pragma unroll
      for (int mf = 0; mf < 4; ++mf) {
        int p = ((zo + kd) * 6 + yo2 + (mf >> 1) + kh) * 34
              + kw + (mf & 1) * 16 + r15;
        Af[mf] = *(const s16x8*)&halo[p * 64 + hi4 * 16];
      }
      __builtin_amdgcn_s_setprio(1);
      #pragma unroll
      for (int mf = 0; mf < 4; ++mf)
        #pragma unroll
        for (int nf = 0; nf < 4; ++nf)
          acc[mf][nf] = __builtin_amdgcn_mfma_f32_16x16x32_bf16(
              Af[mf], Bf[nf], acc[mf][nf], 0, 0, 0);
      __builtin_amdgcn_s_setprio(0);
    }
  };

  // ---- half 0 ----
  stage_halo(0); stage_B(0, 0, 0);
  __syncthreads();                   // halo0 + B(kd0) ready
  stage_B(0, 1, 1);
  run9(0, 0);
  __syncthreads();                   // B(kd1) landed (free drain)
  stage_B(0, 2, 0);                  // buf0 free: kd0 reads done pre-barrier
  run9(1, 1);
  __syncthreads();                   // B(kd2) landed
  run9(2, 0);
  __syncthreads();                   // all halo0/blds reads done

  // ---- half 1 ----
  stage_halo(1); stage_B(1, 0, 1);
  __syncthreads();
  stage_B(1, 1, 0);
  run9(0, 1);
  __syncthreads();
  stage_B(1, 2, 1);
  run9(1, 0);
  __syncthreads();
  run9(2, 1);

  // ---- epilogue (verified 16x16 C/D): full-line coalesced stores ----
  const int z = z0 + zo;
  #pragma unroll
  for (int nf = 0; nf < 4; ++nf) {
    int cout = nf * 16 + r15;
    float bv = bias[cout];
    #pragma unroll
    for (int mf = 0; mf < 4; ++mf) {
      int y  = y0 + yo2 + (mf >> 1);
      int x0 = (mf & 1) * 16 + 4 * hi4;
      float* orow = out + ((size_t)((b * 64 + cout) * 32 + z) * 32 + y) * 32;
      f32x4 v;
      #pragma unroll
      for (int r = 0; r < 4; ++r) v[r] = acc[mf][nf][r] + bv;
      *(f32x4*)&orow[x0] = v;
    }
  }
}

extern "C" void kernel_launch(void* const* d_in, const int* in_sizes, int n_in,
                              void* d_out, int out_size, void* d_ws, size_t ws_size,
                              hipStream_t stream) {
  const float* x    = (const float*)d_in[0];
  const float* wgt  = (const float*)d_in[1];
  const float* bias = (const float*)d_in[2];
  float* out = (float*)d_out;
  char* ws = (char*)d_ws;

  prep_kernel<<<4528, 256, 0, stream>>>(x, wgt,
                                        (unsigned short*)(ws + WS_W_OFF),
                                        (float*)(ws + WS_ZERO_OFF),
                                        (unsigned short*)(ws + WS_XT_OFF));
  conv_kernel<<<256, 512, 0, stream>>>(bias, out, ws);
}